// Round 1
// baseline (291.747 us; speedup 1.0000x reference)
//
#include <hip/hip_runtime.h>
#include <hip/hip_bf16.h>
#include <math.h>

#define BATCH  131072
#define NCLASS 1000
#define FDIM   512
#define CPAD   1024

// ws layout (bytes); total need ~550 KB
//  0      int   counts[1024]
//  4096   int   offsets[1024]
//  8192   int   cursor[1024]
//  12288  float norms_init[1024]
//  16384  float norms_new[1024]
//  20480  float thres[4]
//  20736  float partials[256]
//  24576  int   perm[131072]

__global__ void init_kernel(int* __restrict__ counts) {
    counts[threadIdx.x] = 0;
}

__global__ void bincount_kernel(const int* __restrict__ labels, int* __restrict__ counts) {
    int i = blockIdx.x * 256 + threadIdx.x;
    if (i < BATCH) atomicAdd(&counts[labels[i]], 1);
}

__global__ void scan_kernel(const int* __restrict__ counts, int* __restrict__ offsets,
                            int* __restrict__ cursor) {
    __shared__ int buf[CPAD];
    int t = threadIdx.x;
    buf[t] = counts[t];
    __syncthreads();
    for (int off = 1; off < CPAD; off <<= 1) {
        int x = (t >= off) ? buf[t - off] : 0;
        __syncthreads();
        buf[t] += x;
        __syncthreads();
    }
    int excl = (t == 0) ? 0 : buf[t - 1];
    offsets[t] = excl;
    cursor[t]  = excl;
}

__global__ void scatter_kernel(const int* __restrict__ labels, int* __restrict__ cursor,
                               int* __restrict__ perm) {
    int i = blockIdx.x * 256 + threadIdx.x;
    if (i < BATCH) {
        int pos = atomicAdd(&cursor[labels[i]], 1);
        perm[pos] = i;
    }
}

// One block per class: gather the class's rows via perm, sum, form new center.
// Writes new_center to d_out+1 (scalar stores: base is 4B-aligned only) and
// the squared row norm to norms_new.
__global__ __launch_bounds__(128)
void class_sum_kernel(const float* __restrict__ features,
                      const float* __restrict__ center,
                      const int* __restrict__ offsets,
                      const int* __restrict__ counts,
                      const int* __restrict__ perm,
                      float* __restrict__ out_center,
                      float* __restrict__ norms_new) {
    const int c = blockIdx.x;
    const int t = threadIdx.x;       // 128 threads * float4 = 512 dims
    const int beg = offsets[c];
    const int n   = counts[c];

    float4 acc = make_float4(0.f, 0.f, 0.f, 0.f);
    int r = 0;
    for (; r + 4 <= n; r += 4) {
        int i0 = perm[beg + r + 0];
        int i1 = perm[beg + r + 1];
        int i2 = perm[beg + r + 2];
        int i3 = perm[beg + r + 3];
        float4 v0 = ((const float4*)(features + (size_t)i0 * FDIM))[t];
        float4 v1 = ((const float4*)(features + (size_t)i1 * FDIM))[t];
        float4 v2 = ((const float4*)(features + (size_t)i2 * FDIM))[t];
        float4 v3 = ((const float4*)(features + (size_t)i3 * FDIM))[t];
        acc.x += (v0.x + v1.x) + (v2.x + v3.x);
        acc.y += (v0.y + v1.y) + (v2.y + v3.y);
        acc.z += (v0.z + v1.z) + (v2.z + v3.z);
        acc.w += (v0.w + v1.w) + (v2.w + v3.w);
    }
    for (; r < n; ++r) {
        int i0 = perm[beg + r];
        float4 v0 = ((const float4*)(features + (size_t)i0 * FDIM))[t];
        acc.x += v0.x; acc.y += v0.y; acc.z += v0.z; acc.w += v0.w;
    }

    const float invn = 1.0f / fmaxf((float)n, 1.0f);
    float4 cc = ((const float4*)(center + (size_t)c * FDIM))[t];
    float4 nc;
    nc.x = (cc.x + acc.x) * invn;
    nc.y = (cc.y + acc.y) * invn;
    nc.z = (cc.z + acc.z) * invn;
    nc.w = (cc.w + acc.w) * invn;

    float* o = out_center + (size_t)c * FDIM + t * 4;
    o[0] = nc.x; o[1] = nc.y; o[2] = nc.z; o[3] = nc.w;

    float s = nc.x * nc.x + nc.y * nc.y + nc.z * nc.z + nc.w * nc.w;
    for (int off = 32; off > 0; off >>= 1) s += __shfl_down(s, off, 64);
    __shared__ float w2[2];
    if ((t & 63) == 0) w2[t >> 6] = s;
    __syncthreads();
    if (t == 0) norms_new[c] = w2[0] + w2[1];
}

// Row squared norms of the initial centers (one wave per row).
__global__ __launch_bounds__(64)
void norms_kernel(const float* __restrict__ M, float* __restrict__ norms) {
    const int row  = blockIdx.x;
    const int lane = threadIdx.x;
    const float* p = M + (size_t)row * FDIM;
    float s = 0.f;
#pragma unroll
    for (int i = 0; i < 8; ++i) {
        float v = p[lane + 64 * i];
        s += v * v;
    }
    for (int off = 32; off > 0; off >>= 1) s += __shfl_down(s, off, 64);
    if (lane == 0) norms[row] = s;
}

// Tiled fp32 "GEMM + distance" over the strict upper triangle.
// MODE 0: accumulate sum of dist;  MODE 1: sum of hinge(thres - dist).
// M may be unaligned (d_out+1) -> scalar staging loads only.
template <int MODE>
__global__ __launch_bounds__(256)
void dist_kernel(const float* __restrict__ M,
                 const float* __restrict__ norms,
                 const float* __restrict__ thres_p,
                 float* __restrict__ partials) {
    __shared__ float As[64][36];
    __shared__ float Bs[64][36];
    __shared__ float red[256];
    const int tid = threadIdx.x;

    float local = 0.0f;
    if (blockIdx.x >= blockIdx.y) {   // strict lower-tri blocks contribute 0
        const int bi = blockIdx.y * 64;
        const int bj = blockIdx.x * 64;
        const int tx = tid & 15, ty = tid >> 4;
        float acc[4][4];
#pragma unroll
        for (int ii = 0; ii < 4; ++ii)
#pragma unroll
            for (int jj = 0; jj < 4; ++jj) acc[ii][jj] = 0.0f;

        for (int k0 = 0; k0 < FDIM; k0 += 32) {
            for (int l = tid; l < 64 * 32; l += 256) {
                int rr = l >> 5, kk = l & 31;
                int gi = bi + rr, gj = bj + rr;
                As[rr][kk] = (gi < NCLASS) ? M[(size_t)gi * FDIM + k0 + kk] : 0.0f;
                Bs[rr][kk] = (gj < NCLASS) ? M[(size_t)gj * FDIM + k0 + kk] : 0.0f;
            }
            __syncthreads();
#pragma unroll
            for (int kk = 0; kk < 32; kk += 4) {
                float4 a[4], b[4];
#pragma unroll
                for (int ii = 0; ii < 4; ++ii) a[ii] = *(const float4*)&As[ty * 4 + ii][kk];
#pragma unroll
                for (int jj = 0; jj < 4; ++jj) b[jj] = *(const float4*)&Bs[tx * 4 + jj][kk];
#pragma unroll
                for (int ii = 0; ii < 4; ++ii)
#pragma unroll
                    for (int jj = 0; jj < 4; ++jj) {
                        acc[ii][jj] += a[ii].x * b[jj].x + a[ii].y * b[jj].y +
                                       a[ii].z * b[jj].z + a[ii].w * b[jj].w;
                    }
            }
            __syncthreads();
        }

        const float th = (MODE == 1) ? thres_p[0] : 0.0f;
#pragma unroll
        for (int ii = 0; ii < 4; ++ii)
#pragma unroll
            for (int jj = 0; jj < 4; ++jj) {
                int gi = bi + ty * 4 + ii;
                int gj = bj + tx * 4 + jj;
                if (gi < NCLASS && gj < NCLASS && gj > gi) {
                    float d2 = norms[gi] + norms[gj] - 2.0f * acc[ii][jj];
                    d2 = fmaxf(d2, 0.0f);
                    float dst = (d2 > 0.0f) ? sqrtf(d2) : 0.0f;
                    if (MODE == 1) {
                        if (dst < th) local += th - dst;
                    } else {
                        local += dst;
                    }
                }
            }
    }

    red[tid] = local;
    __syncthreads();
    for (int s = 128; s > 0; s >>= 1) {
        if (tid < s) red[tid] += red[tid + s];
        __syncthreads();
    }
    if (tid == 0) partials[blockIdx.y * gridDim.x + blockIdx.x] = red[0];
}

__global__ void reduce_thres_kernel(const float* __restrict__ partials,
                                    float* __restrict__ thres) {
    __shared__ double red[256];
    int t = threadIdx.x;
    red[t] = (double)partials[t];
    __syncthreads();
    for (int s = 128; s > 0; s >>= 1) {
        if (t < s) red[t] += red[t + s];
        __syncthreads();
    }
    if (t == 0) {
        double sum = 2.0 * red[0];              // strict upper doubled; diagonal dist = 0
        thres[0] = (float)(3.0 * sum / 1.0e6);  // 3 * mean over 1000x1000
    }
}

__global__ void reduce_loss_kernel(const float* __restrict__ partials,
                                   const float* __restrict__ thres,
                                   float* __restrict__ loss) {
    __shared__ double red[256];
    int t = threadIdx.x;
    red[t] = (double)partials[t];
    __syncthreads();
    for (int s = 128; s > 0; s >>= 1) {
        if (t < s) red[t] += red[t + s];
        __syncthreads();
    }
    if (t == 0) {
        // diagonal: dist = 0 < thres -> contributes thres each (1000 entries)
        double sum = 2.0 * red[0] + (double)NCLASS * (double)thres[0];
        loss[0] = (float)(sum / 1.0e6);
    }
}

extern "C" void kernel_launch(void* const* d_in, const int* in_sizes, int n_in,
                              void* d_out, int out_size, void* d_ws, size_t ws_size,
                              hipStream_t stream) {
    const float* features = (const float*)d_in[0];
    const float* center   = (const float*)d_in[1];
    const int*   labels   = (const int*)d_in[2];
    float* out = (float*)d_out;

    char* ws = (char*)d_ws;
    int*   counts     = (int*)(ws + 0);
    int*   offsets    = (int*)(ws + 4096);
    int*   cursor     = (int*)(ws + 8192);
    float* norms_init = (float*)(ws + 12288);
    float* norms_new  = (float*)(ws + 16384);
    float* thres      = (float*)(ws + 20480);
    float* partials   = (float*)(ws + 20736);
    int*   perm       = (int*)(ws + 24576);

    init_kernel<<<1, CPAD, 0, stream>>>(counts);
    bincount_kernel<<<BATCH / 256, 256, 0, stream>>>(labels, counts);
    scan_kernel<<<1, CPAD, 0, stream>>>(counts, offsets, cursor);
    scatter_kernel<<<BATCH / 256, 256, 0, stream>>>(labels, cursor, perm);
    class_sum_kernel<<<NCLASS, 128, 0, stream>>>(features, center, offsets, counts, perm,
                                                 out + 1, norms_new);
    norms_kernel<<<NCLASS, 64, 0, stream>>>(center, norms_init);
    dist_kernel<0><<<dim3(16, 16), 256, 0, stream>>>(center, norms_init, thres, partials);
    reduce_thres_kernel<<<1, 256, 0, stream>>>(partials, thres);
    dist_kernel<1><<<dim3(16, 16), 256, 0, stream>>>(out + 1, norms_new, thres, partials);
    reduce_loss_kernel<<<1, 256, 0, stream>>>(partials, thres, out);
}

// Round 2
// 215.123 us; speedup vs baseline: 1.3562x; 1.3562x over previous
//
#include <hip/hip_runtime.h>
#include <hip/hip_bf16.h>
#include <math.h>

#define BATCH  131072
#define NCLASS 1000
#define FDIM   512
#define CPAD   1024
#define CHUNKS 4

// ws layout (bytes), all 16B-aligned; needs ~10.8 MB (ws is ~1 GB):
//  0        int   counts[1024]
//  4096     int   offsets[1024]
//  8192     int   cursor[1024]
//  12288    float norms_init[1024]
//  16384    float norms_new[1024]
//  20480    float accs[2]  {thres_acc, loss_acc}
//  20488    int   done
//  32768    int   perm[131072]
//  557056   float pbuf[CHUNKS][NCLASS][FDIM]
//  8749056  float wsM[NCLASS][FDIM]   (aligned copy of new centers)

// prep: per-row squared norms of init centers; blocks 0..15 zero counts,
// block 16 zeros the accumulators + ticket.
__global__ __launch_bounds__(64)
void prep_kernel(const float* __restrict__ center, float* __restrict__ norms,
                 int* __restrict__ counts, float* __restrict__ accs) {
    const int row  = blockIdx.x;
    const int lane = threadIdx.x;
    if (row < 16) counts[row * 64 + lane] = 0;
    if (row == 16 && lane < 8) ((int*)accs)[lane] = 0;
    const float* p = center + (size_t)row * FDIM;
    float s = 0.f;
#pragma unroll
    for (int i = 0; i < 8; ++i) {
        float v = p[lane + 64 * i];
        s += v * v;
    }
    for (int off = 32; off > 0; off >>= 1) s += __shfl_down(s, off, 64);
    if (lane == 0) norms[row] = s;
}

__global__ __launch_bounds__(256)
void bincount_kernel(const int* __restrict__ labels, int* __restrict__ counts) {
    int i = blockIdx.x * 256 + threadIdx.x;           // 128 blocks: 32768 int4
    int4 l = ((const int4*)labels)[i];
    atomicAdd(&counts[l.x], 1);
    atomicAdd(&counts[l.y], 1);
    atomicAdd(&counts[l.z], 1);
    atomicAdd(&counts[l.w], 1);
}

__global__ void scan_kernel(const int* __restrict__ counts, int* __restrict__ offsets,
                            int* __restrict__ cursor) {
    __shared__ int buf[CPAD];
    int t = threadIdx.x;
    buf[t] = counts[t];
    __syncthreads();
    for (int off = 1; off < CPAD; off <<= 1) {
        int x = (t >= off) ? buf[t - off] : 0;
        __syncthreads();
        buf[t] += x;
        __syncthreads();
    }
    int excl = (t == 0) ? 0 : buf[t - 1];
    offsets[t] = excl;
    cursor[t]  = excl;
}

__global__ __launch_bounds__(256)
void scatter_kernel(const int* __restrict__ labels, int* __restrict__ cursor,
                    int* __restrict__ perm) {
    int i = blockIdx.x * 256 + threadIdx.x;
    int4 l = ((const int4*)labels)[i];
    int r = i * 4;
    perm[atomicAdd(&cursor[l.x], 1)] = r + 0;
    perm[atomicAdd(&cursor[l.y], 1)] = r + 1;
    perm[atomicAdd(&cursor[l.z], 1)] = r + 2;
    perm[atomicAdd(&cursor[l.w], 1)] = r + 3;
}

// grid (NCLASS, CHUNKS), 128 threads. Each block sums ~n/4 rows of its class.
// perm slice prefetched to LDS so feature-load addresses have no global-load
// dependency -> deep pipelining; 4000 blocks -> ~31 waves/CU for BW.
__global__ __launch_bounds__(128)
void class_sum_chunk(const float* __restrict__ features,
                     const int* __restrict__ offsets,
                     const int* __restrict__ counts,
                     const int* __restrict__ perm,
                     float* __restrict__ pbuf) {
    const int c = blockIdx.x, q = blockIdx.y, t = threadIdx.x;
    const int beg = offsets[c], n = counts[c];
    const int per = (n + CHUNKS - 1) / CHUNKS;
    const int s   = q * per;
    const int e   = min(n, s + per);
    __shared__ int lp[128];
    float4 acc = make_float4(0.f, 0.f, 0.f, 0.f);
    for (int base = s; base < e; base += 128) {
        const int mm = min(128, e - base);
        __syncthreads();
        if (t < mm) lp[t] = perm[beg + base + t];
        __syncthreads();
        int r = 0;
        for (; r + 4 <= mm; r += 4) {
            int i0 = lp[r], i1 = lp[r + 1], i2 = lp[r + 2], i3 = lp[r + 3];
            float4 v0 = ((const float4*)(features + (size_t)i0 * FDIM))[t];
            float4 v1 = ((const float4*)(features + (size_t)i1 * FDIM))[t];
            float4 v2 = ((const float4*)(features + (size_t)i2 * FDIM))[t];
            float4 v3 = ((const float4*)(features + (size_t)i3 * FDIM))[t];
            acc.x += (v0.x + v1.x) + (v2.x + v3.x);
            acc.y += (v0.y + v1.y) + (v2.y + v3.y);
            acc.z += (v0.z + v1.z) + (v2.z + v3.z);
            acc.w += (v0.w + v1.w) + (v2.w + v3.w);
        }
        for (; r < mm; ++r) {
            int i0 = lp[r];
            float4 v0 = ((const float4*)(features + (size_t)i0 * FDIM))[t];
            acc.x += v0.x; acc.y += v0.y; acc.z += v0.z; acc.w += v0.w;
        }
    }
    ((float4*)(pbuf + ((size_t)q * NCLASS + c) * FDIM))[t] = acc;
}

// 1000 blocks x 128: combine 4 partials + center, write new center to
// d_out+1 (scalar: unaligned base), aligned ws copy, and its squared norm.
__global__ __launch_bounds__(128)
void finalize_kernel(const float* __restrict__ center,
                     const float* __restrict__ pbuf,
                     const int* __restrict__ counts,
                     float* __restrict__ out_center,
                     float* __restrict__ wsM,
                     float* __restrict__ norms_new) {
    const int c = blockIdx.x, t = threadIdx.x;
    float4 s0 = ((const float4*)(pbuf + ((size_t)0 * NCLASS + c) * FDIM))[t];
    float4 s1 = ((const float4*)(pbuf + ((size_t)1 * NCLASS + c) * FDIM))[t];
    float4 s2 = ((const float4*)(pbuf + ((size_t)2 * NCLASS + c) * FDIM))[t];
    float4 s3 = ((const float4*)(pbuf + ((size_t)3 * NCLASS + c) * FDIM))[t];
    float4 cc = ((const float4*)(center + (size_t)c * FDIM))[t];
    const float invn = 1.0f / fmaxf((float)counts[c], 1.0f);
    float4 nc;
    nc.x = (cc.x + ((s0.x + s1.x) + (s2.x + s3.x))) * invn;
    nc.y = (cc.y + ((s0.y + s1.y) + (s2.y + s3.y))) * invn;
    nc.z = (cc.z + ((s0.z + s1.z) + (s2.z + s3.z))) * invn;
    nc.w = (cc.w + ((s0.w + s1.w) + (s2.w + s3.w))) * invn;
    float* o = out_center + (size_t)c * FDIM + t * 4;
    o[0] = nc.x; o[1] = nc.y; o[2] = nc.z; o[3] = nc.w;
    ((float4*)(wsM + (size_t)c * FDIM))[t] = nc;
    float s = nc.x * nc.x + nc.y * nc.y + nc.z * nc.z + nc.w * nc.w;
    for (int off = 32; off > 0; off >>= 1) s += __shfl_down(s, off, 64);
    __shared__ float w2[2];
    if ((t & 63) == 0) w2[t >> 6] = s;
    __syncthreads();
    if (t == 0) norms_new[c] = w2[0] + w2[1];
}

// Tiled fp32 GEMM+distance over the strict upper triangle, reduction fused
// via f32 atomics. MODE 0: sum of dist -> acc[0]. MODE 1: sum of hinge ->
// acc[1], last block (ticket) writes the final loss to out0.
template <int MODE>
__global__ __launch_bounds__(256)
void dist_kernel(const float* __restrict__ M,
                 const float* __restrict__ norms,
                 float* __restrict__ accs,
                 int* __restrict__ done,
                 float* __restrict__ out0) {
    __shared__ float As[64][36];
    __shared__ float Bs[64][36];
    __shared__ float red[256];
    const int tid = threadIdx.x;
    const bool active = (blockIdx.x >= blockIdx.y);

    if (active) {
        const int bi = blockIdx.y * 64;
        const int bj = blockIdx.x * 64;
        const int tx = tid & 15, ty = tid >> 4;
        float acc[4][4];
#pragma unroll
        for (int ii = 0; ii < 4; ++ii)
#pragma unroll
            for (int jj = 0; jj < 4; ++jj) acc[ii][jj] = 0.0f;

        for (int k0 = 0; k0 < FDIM; k0 += 32) {
#pragma unroll
            for (int l = tid; l < 512; l += 256) {
                const int rr = l >> 3, k4 = l & 7;
                const int gi = bi + rr, gj = bj + rr;
                const float4 z = make_float4(0.f, 0.f, 0.f, 0.f);
                float4 av = (gi < NCLASS) ? ((const float4*)(M + (size_t)gi * FDIM + k0))[k4] : z;
                float4 bv = (gj < NCLASS) ? ((const float4*)(M + (size_t)gj * FDIM + k0))[k4] : z;
                *(float4*)&As[rr][k4 * 4] = av;
                *(float4*)&Bs[rr][k4 * 4] = bv;
            }
            __syncthreads();
#pragma unroll
            for (int kk = 0; kk < 32; kk += 4) {
                float4 a[4], b[4];
#pragma unroll
                for (int ii = 0; ii < 4; ++ii) a[ii] = *(const float4*)&As[ty * 4 + ii][kk];
#pragma unroll
                for (int jj = 0; jj < 4; ++jj) b[jj] = *(const float4*)&Bs[tx * 4 + jj][kk];
#pragma unroll
                for (int ii = 0; ii < 4; ++ii)
#pragma unroll
                    for (int jj = 0; jj < 4; ++jj) {
                        acc[ii][jj] += a[ii].x * b[jj].x + a[ii].y * b[jj].y +
                                       a[ii].z * b[jj].z + a[ii].w * b[jj].w;
                    }
            }
            __syncthreads();
        }

        const float th = (MODE == 1) ? (6.0f * accs[0] * 1e-6f) : 0.0f;
        float local = 0.0f;
#pragma unroll
        for (int ii = 0; ii < 4; ++ii)
#pragma unroll
            for (int jj = 0; jj < 4; ++jj) {
                const int gi = bi + ty * 4 + ii;
                const int gj = bj + tx * 4 + jj;
                if (gi < NCLASS && gj < NCLASS && gj > gi) {
                    float d2 = norms[gi] + norms[gj] - 2.0f * acc[ii][jj];
                    d2 = fmaxf(d2, 0.0f);
                    float dst = (d2 > 0.0f) ? sqrtf(d2) : 0.0f;
                    if (MODE == 1) {
                        if (dst < th) local += th - dst;
                    } else {
                        local += dst;
                    }
                }
            }

        red[tid] = local;
        __syncthreads();
        for (int s = 128; s > 0; s >>= 1) {
            if (tid < s) red[tid] += red[tid + s];
            __syncthreads();
        }
        if (tid == 0) atomicAdd(&accs[MODE], red[0]);
    }

    if (MODE == 1) {
        if (tid == 0) {
            __threadfence();
            const int old = atomicAdd(done, 1);
            if (old == 255) {                         // last of the 16x16 grid
                const double ls = (double)atomicAdd(&accs[1], 0.0f);
                const double th = 6.0 * (double)accs[0] * 1e-6;
                out0[0] = (float)((2.0 * ls + (double)NCLASS * th) * 1e-6);
            }
        }
    }
}

extern "C" void kernel_launch(void* const* d_in, const int* in_sizes, int n_in,
                              void* d_out, int out_size, void* d_ws, size_t ws_size,
                              hipStream_t stream) {
    const float* features = (const float*)d_in[0];
    const float* center   = (const float*)d_in[1];
    const int*   labels   = (const int*)d_in[2];
    float* out = (float*)d_out;

    char* ws = (char*)d_ws;
    int*   counts     = (int*)(ws + 0);
    int*   offsets    = (int*)(ws + 4096);
    int*   cursor     = (int*)(ws + 8192);
    float* norms_init = (float*)(ws + 12288);
    float* norms_new  = (float*)(ws + 16384);
    float* accs       = (float*)(ws + 20480);
    int*   done       = (int*)(ws + 20488);
    int*   perm       = (int*)(ws + 32768);
    float* pbuf       = (float*)(ws + 557056);
    float* wsM        = (float*)(ws + 8749056);

    prep_kernel<<<NCLASS, 64, 0, stream>>>(center, norms_init, counts, accs);
    bincount_kernel<<<BATCH / 1024, 256, 0, stream>>>(labels, counts);
    scan_kernel<<<1, CPAD, 0, stream>>>(counts, offsets, cursor);
    scatter_kernel<<<BATCH / 1024, 256, 0, stream>>>(labels, cursor, perm);
    class_sum_chunk<<<dim3(NCLASS, CHUNKS), 128, 0, stream>>>(features, offsets, counts,
                                                              perm, pbuf);
    finalize_kernel<<<NCLASS, 128, 0, stream>>>(center, pbuf, counts, out + 1, wsM,
                                                norms_new);
    dist_kernel<0><<<dim3(16, 16), 256, 0, stream>>>(center, norms_init, accs, done, out);
    dist_kernel<1><<<dim3(16, 16), 256, 0, stream>>>(wsM, norms_new, accs, done, out);
}